// Round 7
// baseline (303.144 us; speedup 1.0000x reference)
//
#include <hip/hip_runtime.h>
#include <hip/hip_bf16.h>
#include <cstdint>

// MultiHeadSelfAttention: B=4, N=2048, C=1024, H=16, D=64
// R7 (delta from R6):
//  - attn: P LDS round-trip software-pipelined across kt iterations with a
//    parity double-buffer: read P(i-1) issued before QK(i) MFMAs, PV(i-1)
//    after -> store-to-load latency hidden by the QK block + backedge.
//  - cvt_kernel + trans_w merged into one dispatch (prep_kernel).

typedef __attribute__((ext_vector_type(8))) short short8;    // 8 bf16
typedef __attribute__((ext_vector_type(4))) float floatx4;

#if __has_builtin(__builtin_amdgcn_exp2f)
#define EXP2F(x) __builtin_amdgcn_exp2f(x)
#else
#define EXP2F(x) __expf((x) * 0.6931471805599453f)
#endif

__device__ __forceinline__ unsigned short f2bf(float f) {
  unsigned u = __float_as_uint(f);
  unsigned r = u + 0x7fffu + ((u >> 16) & 1u);   // RNE
  return (unsigned short)(r >> 16);
}

__device__ __forceinline__ void async16(const void* g, void* l) {
  __builtin_amdgcn_global_load_lds(
      (__attribute__((address_space(1))) void*)(void*)(uintptr_t)g,
      (__attribute__((address_space(3))) void*)l, 16, 0, 0);
}

// ------------------------------------------- prep: x cvt + 4x W^T (merged)
__global__ __launch_bounds__(256) void prep_kernel(
    const float* __restrict__ x, unsigned short* __restrict__ xb,
    const float* __restrict__ W0, const float* __restrict__ W1,
    const float* __restrict__ W2, const float* __restrict__ W3,
    unsigned short* __restrict__ T0, unsigned short* __restrict__ T1,
    unsigned short* __restrict__ T2, unsigned short* __restrict__ T3) {
  const int tid = threadIdx.x;
  int blk = blockIdx.x;
  if (blk < 8192) {               // ---- x f32 -> bf16
    int i = (blk * 256 + tid) * 4;
    float4 v = *(const float4*)(x + i);
    ushort4 o;
    o.x = f2bf(v.x); o.y = f2bf(v.y); o.z = f2bf(v.z); o.w = f2bf(v.w);
    *(ushort4*)(xb + i) = o;
  } else {                        // ---- W transpose+convert, 32x32 tiles
    int t = blk - 8192;
    int z = t >> 10, tile = t & 1023;
    const float* W = z == 0 ? W0 : z == 1 ? W1 : z == 2 ? W2 : W3;
    unsigned short* T = z == 0 ? T0 : z == 1 ? T1 : z == 2 ? T2 : T3;
    __shared__ float tb[32][33];
    int tx = tid & 31, ty = tid >> 5;            // 32 x 8
    int bx = (tile & 31) * 32, by = (tile >> 5) * 32;
#pragma unroll
    for (int i = 0; i < 4; ++i)
      tb[ty + i * 8][tx] = W[(size_t)(by + ty + i * 8) * 1024 + bx + tx];
    __syncthreads();
#pragma unroll
    for (int i = 0; i < 4; ++i)
      T[(size_t)(bx + ty + i * 8) * 1024 + by + tx] = f2bf(tb[tx][ty + i * 8]);
  }
}

// ------------------------------------------- fused QKV projection (M x 3072)
// A: xb [8192][1024], BT: wcat^T [3072][1024]. Outputs frag-major Q/K and
// key-interleaved frag-major V^T. Epilogue: LDS frag-image + coalesced store.
__global__ __launch_bounds__(256) void gemm_qkv(
    const unsigned short* __restrict__ A, const unsigned short* __restrict__ BT,
    const float* __restrict__ bq, const float* __restrict__ bk,
    const float* __restrict__ bv,
    unsigned short* __restrict__ Qo, unsigned short* __restrict__ Ko,
    unsigned short* __restrict__ Vo) {
  constexpr int Kd = 1024;
  __shared__ unsigned short sm[8192];   // 16 KB: As|Bs staging, then frag image
  unsigned short* As = sm;
  unsigned short* Bs = sm + 4096;
  const int tid = threadIdx.x;
  const int wave = tid >> 6, lane = tid & 63;
  const int quad = lane >> 4, l16 = lane & 15;
  const int wm = (wave & 1) * 64, wn = (wave >> 1) * 64;
  const int m0 = blockIdx.x * 128, n0 = blockIdx.y * 128;
  const int mid = blockIdx.y >> 3;                 // 0=Q 1=K 2=V
  const float* bias = mid == 0 ? bq : mid == 1 ? bk : bv;
  const float scale = mid == 0 ? 0.180336880021082f : 1.0f;  // Q: 0.125*log2(e)

  floatx4 acc[4][4] = {};
  const unsigned short* Ag = A + (size_t)m0 * Kd;
  const unsigned short* Bg = BT + (size_t)n0 * Kd;

  for (int k0 = 0; k0 < Kd; k0 += 32) {
    __syncthreads();
#pragma unroll
    for (int p = 0; p < 2; ++p) {
      int c = wave * 128 + p * 64 + lane;
      int row = c >> 2, kp = (c & 3) * 8;
      async16(Ag + (size_t)row * Kd + k0 + kp, (char*)As + (size_t)(wave * 128 + p * 64) * 16);
      async16(Bg + (size_t)row * Kd + k0 + kp, (char*)Bs + (size_t)(wave * 128 + p * 64) * 16);
    }
    __syncthreads();
    short8 a[4], b[4];
#pragma unroll
    for (int i = 0; i < 4; ++i) {
      a[i] = *(const short8*)(As + (wm + i * 16 + l16) * 32 + quad * 8);
      b[i] = *(const short8*)(Bs + (wn + i * 16 + l16) * 32 + quad * 8);
    }
#pragma unroll
    for (int i = 0; i < 4; ++i)
#pragma unroll
      for (int j = 0; j < 4; ++j)
        acc[i][j] = __builtin_amdgcn_mfma_f32_16x16x32_bf16(a[i], b[j], acc[i][j], 0, 0, 0);
  }

  // ---- epilogue: two passes over head-halves of the 128-col tile
  const int b = m0 >> 11;
  const int ni0 = m0 & 2047;
#pragma unroll
  for (int p = 0; p < 2; ++p) {
    __syncthreads();
    if ((wave >> 1) == p) {   // 2 waves own this pass's 64 cols
#pragma unroll
      for (int j = 0; j < 4; ++j) {
        int d = j * 16 + l16;                       // 0..63 within head
        int cn = (n0 & 1023) + p * 64 + d;
        float bb = bias[cn];
#pragma unroll
        for (int i = 0; i < 4; ++i) {
#pragma unroll
          for (int r = 0; r < 4; ++r) {
            unsigned short hv = f2bf((acc[i][j][r] + bb) * scale);
            int off;
            if (mid == 2)     // V frag image (key-interleaved)
              off = (((wm >> 5) + (i >> 1)) * 4 + j) * 512 + quad * 128 + l16 * 8 + r * 2 + (i & 1);
            else              // Q/K frag image
              off = (((wm >> 4) + i) * 2 + (d >> 5)) * 512 + ((d & 31) >> 3) * 128 + (quad * 4 + r) * 8 + (l16 & 7);
            sm[off] = hv;
          }
        }
      }
    }
    __syncthreads();
    int h = ((n0 & 1023) + p * 64) >> 6;
    size_t bh = (size_t)b * 16 + h;
    unsigned short* dstbase;
    if (mid == 2) dstbase = Vo + ((bh * 64 + (ni0 >> 5)) * 4) * 512;
    else dstbase = (mid ? Ko : Qo) + ((bh * 128 + (ni0 >> 4)) * 2) * 512;
#pragma unroll
    for (int it = 0; it < 4; ++it) {
      int c = it * 256 + tid;
      *(short8*)(dstbase + c * 8) = *(const short8*)(sm + c * 8);
    }
  }
}

// --------------------------------------------------------------- attention
// Block: 4 waves = 2 q-groups (32 rows) x 2 key-halves (32 kt each).
// Grid 2048 = 64 bh x 32 q-blocks of 64 rows. No barriers in main loop.
// P LDS round-trip pipelined across kt with parity double-buffer.
__global__ __launch_bounds__(256) void attn_kernel(
    const unsigned short* __restrict__ Qs, const unsigned short* __restrict__ Ksw,
    const unsigned short* __restrict__ Vsw, unsigned short* __restrict__ O) {
  __shared__ __align__(16) char smem[20480];
  // phase 1: P double-buffer: wave w parity p at w*5120 + p*2560 bytes
  // phase 2 (epilogue): buf 2 x 32 x 68 f32 + lbuf 64 f32 (17664 B)

  const int tid = threadIdx.x, wave = tid >> 6, lane = tid & 63;
  const int quad = lane >> 4, l16 = lane & 15;
  const int wk = wave & 1, wqi = wave >> 1;
  int blk = blockIdx.x;
  int xcd = blk & 7, slot = blk >> 3;
  int bh = (slot & 7) * 8 + xcd, qb = slot >> 3;   // qb: 0..31 (64-row blocks)

  unsigned short* Pw0 = (unsigned short*)(smem + wave * 5120);
  unsigned short* Pw1 = (unsigned short*)(smem + wave * 5120 + 2560);

  // Q A-frags (2 row-tiles x 2 k-halves)
  short8 aq[2][2];
#pragma unroll
  for (int rt = 0; rt < 2; ++rt)
#pragma unroll
    for (int kk = 0; kk < 2; ++kk)
      aq[rt][kk] = *(const short8*)(Qs +
          (((size_t)bh * 128 + qb * 4 + wqi * 2 + rt) * 2 + kk) * 512 + lane * 8);

  short8 ones;
#pragma unroll
  for (int i = 0; i < 8; ++i) ones[i] = (short)0x3F80;   // bf16 1.0

  const float MSUB = 17.3123404906675611f;   // 12*log2(e); scores in log2 units
  floatx4 mneg;
#pragma unroll
  for (int i = 0; i < 4; ++i) mneg[i] = -MSUB;

  floatx4 acc_o[2][4] = {};
  floatx4 acc_l[2] = {};

  const unsigned short* kptr = Ksw + (size_t)bh * 128 * 2 * 512 + (size_t)wk * 32 * 2048;
  const unsigned short* vptr = Vsw + (size_t)bh * 64 * 4 * 512 + (size_t)wk * 32 * 2048;

  short8 kf[2][2], vf[4];
  floatx4 sacc[2][2];

  // ---- prologue: kti = 0
#pragma unroll
  for (int ct = 0; ct < 2; ++ct)
#pragma unroll
    for (int kk = 0; kk < 2; ++kk)
      kf[ct][kk] = *(const short8*)(kptr + (ct * 2 + kk) * 512 + lane * 8);
#pragma unroll
  for (int nt = 0; nt < 4; ++nt)
    vf[nt] = *(const short8*)(vptr + nt * 512 + lane * 8);
  kptr += 2048; vptr += 2048;
#pragma unroll
  for (int rt = 0; rt < 2; ++rt)
#pragma unroll
    for (int ct = 0; ct < 2; ++ct) {
      sacc[rt][ct] = __builtin_amdgcn_mfma_f32_16x16x32_bf16(aq[rt][0], kf[ct][0], mneg, 0, 0, 0);
      sacc[rt][ct] = __builtin_amdgcn_mfma_f32_16x16x32_bf16(aq[rt][1], kf[ct][1], sacc[rt][ct], 0, 0, 0);
    }
#pragma unroll
  for (int rt = 0; rt < 2; ++rt)
#pragma unroll
    for (int r = 0; r < 4; ++r) {
      float pe = EXP2F(sacc[rt][0][r]);
      float po = EXP2F(sacc[rt][1][r]);
      unsigned pk = __builtin_amdgcn_perm(__float_as_uint(po), __float_as_uint(pe), 0x07060302u);
      ((unsigned*)(Pw0 + (rt * 16 + quad * 4 + r) * 40))[l16] = pk;
    }

  // ---- main loop: kti = 1..31; PV(i-1) interleaved under QK(i)
  for (int kti = 1; kti < 32; ++kti) {
    unsigned short* Pprev = (kti & 1) ? Pw0 : Pw1;
    unsigned short* Pcur  = (kti & 1) ? Pw1 : Pw0;
    // K frag loads for this iter
    short8 kn[2][2];
#pragma unroll
    for (int ct = 0; ct < 2; ++ct)
#pragma unroll
      for (int kk = 0; kk < 2; ++kk)
        kn[ct][kk] = *(const short8*)(kptr + (ct * 2 + kk) * 512 + lane * 8);
    // issue P(i-1) reads early; consumed after QK
    short8 ap[2];
#pragma unroll
    for (int rt = 0; rt < 2; ++rt)
      ap[rt] = *(const short8*)(Pprev + (rt * 16 + l16) * 40 + quad * 8);
    // QK(i)
#pragma unroll
    for (int rt = 0; rt < 2; ++rt)
#pragma unroll
      for (int ct = 0; ct < 2; ++ct) {
        sacc[rt][ct] = __builtin_amdgcn_mfma_f32_16x16x32_bf16(aq[rt][0], kn[ct][0], mneg, 0, 0, 0);
        sacc[rt][ct] = __builtin_amdgcn_mfma_f32_16x16x32_bf16(aq[rt][1], kn[ct][1], sacc[rt][ct], 0, 0, 0);
      }
    // PV(i-1) with previous vf
#pragma unroll
    for (int rt = 0; rt < 2; ++rt) {
      acc_l[rt] = __builtin_amdgcn_mfma_f32_16x16x32_bf16(ap[rt], ones, acc_l[rt], 0, 0, 0);
#pragma unroll
      for (int nt = 0; nt < 4; ++nt)
        acc_o[rt][nt] = __builtin_amdgcn_mfma_f32_16x16x32_bf16(ap[rt], vf[nt], acc_o[rt][nt], 0, 0, 0);
    }
    // V frag loads for this iter (reuse vf regs after PV issue)
#pragma unroll
    for (int nt = 0; nt < 4; ++nt)
      vf[nt] = *(const short8*)(vptr + nt * 512 + lane * 8);
    kptr += 2048; vptr += 2048;
    // exp + pack + write P(i)
#pragma unroll
    for (int rt = 0; rt < 2; ++rt)
#pragma unroll
      for (int r = 0; r < 4; ++r) {
        float pe = EXP2F(sacc[rt][0][r]);
        float po = EXP2F(sacc[rt][1][r]);
        unsigned pk = __builtin_amdgcn_perm(__float_as_uint(po), __float_as_uint(pe), 0x07060302u);
        ((unsigned*)(Pcur + (rt * 16 + quad * 4 + r) * 40))[l16] = pk;
      }
  }
  // ---- epilogue PV for kti=31 (parity 1)
#pragma unroll
  for (int rt = 0; rt < 2; ++rt) {
    short8 apf = *(const short8*)(Pw1 + (rt * 16 + l16) * 40 + quad * 8);
    acc_l[rt] = __builtin_amdgcn_mfma_f32_16x16x32_bf16(apf, ones, acc_l[rt], 0, 0, 0);
#pragma unroll
    for (int nt = 0; nt < 4; ++nt)
      acc_o[rt][nt] = __builtin_amdgcn_mfma_f32_16x16x32_bf16(apf, vf[nt], acc_o[rt][nt], 0, 0, 0);
  }

  // ---- combine key halves, normalize, store
  float* buf = (float*)smem + wqi * 2176;          // 32 x 68 f32
  float* lbuf = (float*)(smem + 17408);            // 64 f32
  __syncthreads();
  if (wk == 1) {
#pragma unroll
    for (int rt = 0; rt < 2; ++rt)
#pragma unroll
      for (int r = 0; r < 4; ++r) {
        int row = rt * 16 + quad * 4 + r;
#pragma unroll
        for (int nt = 0; nt < 4; ++nt)
          buf[row * 68 + nt * 16 + l16] = acc_o[rt][nt][r];
        if (l16 == 0) lbuf[wqi * 32 + row] = acc_l[rt][r];
      }
  }
  __syncthreads();
  if (wk == 0) {
    const int b = bh >> 4, h = bh & 15;
#pragma unroll
    for (int rt = 0; rt < 2; ++rt)
#pragma unroll
      for (int r = 0; r < 4; ++r) {
        int row = rt * 16 + quad * 4 + r;
        float linv = 1.0f / (acc_l[rt][r] + lbuf[wqi * 32 + row]);
        int grow = qb * 64 + wqi * 32 + row;
#pragma unroll
        for (int nt = 0; nt < 4; ++nt) {
          float v = (acc_o[rt][nt][r] + buf[row * 68 + nt * 16 + l16]) * linv;
          O[((size_t)b * 2048 + grow) * 1024 + h * 64 + nt * 16 + l16] = f2bf(v);
        }
      }
  }
}

// ------------------------------------------------------------- output GEMM
__global__ __launch_bounds__(256) void gemm_out(
    const unsigned short* __restrict__ A, const unsigned short* __restrict__ BT,
    const float* __restrict__ bias, float* __restrict__ of) {
  constexpr int Kd = 1024;
  __shared__ unsigned short As[128 * 32];
  __shared__ unsigned short Bs[128 * 32];
  const int tid = threadIdx.x;
  const int wave = tid >> 6, lane = tid & 63;
  const int quad = lane >> 4, l16 = lane & 15;
  const int wm = (wave & 1) * 64, wn = (wave >> 1) * 64;
  const int m0 = blockIdx.x * 128, n0 = blockIdx.y * 128;

  floatx4 acc[4][4] = {};
  const unsigned short* Ag = A + (size_t)m0 * Kd;
  const unsigned short* Bg = BT + (size_t)n0 * Kd;

  for (int k0 = 0; k0 < Kd; k0 += 32) {
    __syncthreads();
#pragma unroll
    for (int p = 0; p < 2; ++p) {
      int c = wave * 128 + p * 64 + lane;
      int row = c >> 2, kp = (c & 3) * 8;
      async16(Ag + (size_t)row * Kd + k0 + kp, (char*)As + (size_t)(wave * 128 + p * 64) * 16);
      async16(Bg + (size_t)row * Kd + k0 + kp, (char*)Bs + (size_t)(wave * 128 + p * 64) * 16);
    }
    __syncthreads();
    short8 a[4], b[4];
#pragma unroll
    for (int i = 0; i < 4; ++i) {
      a[i] = *(const short8*)(As + (wm + i * 16 + l16) * 32 + quad * 8);
      b[i] = *(const short8*)(Bs + (wn + i * 16 + l16) * 32 + quad * 8);
    }
#pragma unroll
    for (int i = 0; i < 4; ++i)
#pragma unroll
      for (int j = 0; j < 4; ++j)
        acc[i][j] = __builtin_amdgcn_mfma_f32_16x16x32_bf16(a[i], b[j], acc[i][j], 0, 0, 0);
  }

#pragma unroll
  for (int j = 0; j < 4; ++j) {
    int col = n0 + wn + j * 16 + l16;
    float bb = bias[col];
#pragma unroll
    for (int i = 0; i < 4; ++i) {
      int rbase = m0 + wm + i * 16 + quad * 4;
#pragma unroll
      for (int r = 0; r < 4; ++r)
        of[(size_t)(rbase + r) * 1024 + col] = acc[i][j][r] + bb;
    }
  }
}

// ---------------------------------------------------------------- launch
extern "C" void kernel_launch(void* const* d_in, const int* in_sizes, int n_in,
                              void* d_out, int out_size, void* d_ws, size_t ws_size,
                              hipStream_t stream) {
  const float* x  = (const float*)d_in[0];
  const float* Wq = (const float*)d_in[1];
  const float* bq = (const float*)d_in[2];
  const float* Wk = (const float*)d_in[3];
  const float* bk = (const float*)d_in[4];
  const float* Wv = (const float*)d_in[5];
  const float* bv = (const float*)d_in[6];
  const float* Wo = (const float*)d_in[7];
  const float* bo = (const float*)d_in[8];

  char* ws = (char*)d_ws;
  unsigned short* xb  = (unsigned short*)(ws);                 // 16 MiB
  unsigned short* wqt = (unsigned short*)(ws + (16u << 20));   // 2 MiB each, contiguous
  unsigned short* wkt = (unsigned short*)(ws + (18u << 20));
  unsigned short* wvt = (unsigned short*)(ws + (20u << 20));
  unsigned short* wot = (unsigned short*)(ws + (22u << 20));
  unsigned short* Qb  = (unsigned short*)(ws + (24u << 20));   // 16 MiB each
  unsigned short* Kb  = (unsigned short*)(ws + (40u << 20));
  unsigned short* Vtb = (unsigned short*)(ws + (56u << 20));
  unsigned short* Ob  = (unsigned short*)(ws + (72u << 20));   // total 88 MiB

  prep_kernel<<<dim3(12288), 256, 0, stream>>>(x, xb, Wq, Wk, Wv, Wo, wqt, wkt, wvt, wot);
  gemm_qkv<<<dim3(64, 24), 256, 0, stream>>>(xb, wqt, bq, bk, bv, Qb, Kb, Vtb);
  attn_kernel<<<dim3(2048), 256, 0, stream>>>(Qb, Kb, Vtb, Ob);
  gemm_out<<<dim3(64, 8), 256, 0, stream>>>(Ob, wot, bo, (float*)d_out);
}

// Round 9
// 285.257 us; speedup vs baseline: 1.0627x; 1.0627x over previous
//
#include <hip/hip_runtime.h>
#include <hip/hip_bf16.h>
#include <cstdint>

// MultiHeadSelfAttention: B=4, N=2048, C=1024, H=16, D=64
// R9 (delta from R8):
//  - exp back to EXP2F macro (R8's inline-asm v_exp_f32 broke correctness:
//    TRANS->VALU wait-state hazard not inserted around opaque INLINEASM).
//  - gemm_qkv back to R5 direct-scatter epilogue (frag-image was ~8us slower).
//  - keep __launch_bounds__(256,4) on attn (tests AGPR-pressure theory).

typedef __attribute__((ext_vector_type(8))) short short8;    // 8 bf16
typedef __attribute__((ext_vector_type(4))) float floatx4;

#if __has_builtin(__builtin_amdgcn_exp2f)
#define EXP2F(x) __builtin_amdgcn_exp2f(x)
#else
#define EXP2F(x) __expf((x) * 0.6931471805599453f)
#endif

__device__ __forceinline__ unsigned short f2bf(float f) {
  unsigned u = __float_as_uint(f);
  unsigned r = u + 0x7fffu + ((u >> 16) & 1u);   // RNE
  return (unsigned short)(r >> 16);
}

__device__ __forceinline__ void async16(const void* g, void* l) {
  __builtin_amdgcn_global_load_lds(
      (__attribute__((address_space(1))) void*)(void*)(uintptr_t)g,
      (__attribute__((address_space(3))) void*)l, 16, 0, 0);
}

// ------------------------------------------- prep: x cvt + 4x W^T (merged)
__global__ __launch_bounds__(256) void prep_kernel(
    const float* __restrict__ x, unsigned short* __restrict__ xb,
    const float* __restrict__ W0, const float* __restrict__ W1,
    const float* __restrict__ W2, const float* __restrict__ W3,
    unsigned short* __restrict__ T0, unsigned short* __restrict__ T1,
    unsigned short* __restrict__ T2, unsigned short* __restrict__ T3) {
  const int tid = threadIdx.x;
  int blk = blockIdx.x;
  if (blk < 8192) {               // ---- x f32 -> bf16
    int i = (blk * 256 + tid) * 4;
    float4 v = *(const float4*)(x + i);
    ushort4 o;
    o.x = f2bf(v.x); o.y = f2bf(v.y); o.z = f2bf(v.z); o.w = f2bf(v.w);
    *(ushort4*)(xb + i) = o;
  } else {                        // ---- W transpose+convert, 32x32 tiles
    int t = blk - 8192;
    int z = t >> 10, tile = t & 1023;
    const float* W = z == 0 ? W0 : z == 1 ? W1 : z == 2 ? W2 : W3;
    unsigned short* T = z == 0 ? T0 : z == 1 ? T1 : z == 2 ? T2 : T3;
    __shared__ float tb[32][33];
    int tx = tid & 31, ty = tid >> 5;            // 32 x 8
    int bx = (tile & 31) * 32, by = (tile >> 5) * 32;
#pragma unroll
    for (int i = 0; i < 4; ++i)
      tb[ty + i * 8][tx] = W[(size_t)(by + ty + i * 8) * 1024 + bx + tx];
    __syncthreads();
#pragma unroll
    for (int i = 0; i < 4; ++i)
      T[(size_t)(bx + ty + i * 8) * 1024 + by + tx] = f2bf(tb[tx][ty + i * 8]);
  }
}

// ------------------------------------------- fused QKV projection (M x 3072)
// A: xb [8192][1024], BT: wcat^T [3072][1024]. Outputs frag-major Q/K and
// key-interleaved frag-major V^T. Direct 2B scatter epilogue (R5 style).
__global__ __launch_bounds__(256) void gemm_qkv(
    const unsigned short* __restrict__ A, const unsigned short* __restrict__ BT,
    const float* __restrict__ bq, const float* __restrict__ bk,
    const float* __restrict__ bv,
    unsigned short* __restrict__ Qo, unsigned short* __restrict__ Ko,
    unsigned short* __restrict__ Vo) {
  constexpr int Kd = 1024;
  __shared__ unsigned short As[128 * 32];
  __shared__ unsigned short Bs[128 * 32];
  const int tid = threadIdx.x;
  const int wave = tid >> 6, lane = tid & 63;
  const int quad = lane >> 4, l16 = lane & 15;
  const int wm = (wave & 1) * 64, wn = (wave >> 1) * 64;
  const int m0 = blockIdx.x * 128, n0 = blockIdx.y * 128;
  const int mid = blockIdx.y >> 3;                 // 0=Q 1=K 2=V
  const float* bias = mid == 0 ? bq : mid == 1 ? bk : bv;
  const float scale = mid == 0 ? 0.180336880021082f : 1.0f;  // Q: 0.125*log2(e)

  floatx4 acc[4][4] = {};
  const unsigned short* Ag = A + (size_t)m0 * Kd;
  const unsigned short* Bg = BT + (size_t)n0 * Kd;

  for (int k0 = 0; k0 < Kd; k0 += 32) {
    __syncthreads();
#pragma unroll
    for (int p = 0; p < 2; ++p) {
      int c = wave * 128 + p * 64 + lane;
      int row = c >> 2, kp = (c & 3) * 8;
      async16(Ag + (size_t)row * Kd + k0 + kp, (char*)As + (size_t)(wave * 128 + p * 64) * 16);
      async16(Bg + (size_t)row * Kd + k0 + kp, (char*)Bs + (size_t)(wave * 128 + p * 64) * 16);
    }
    __syncthreads();
    short8 a[4], b[4];
#pragma unroll
    for (int i = 0; i < 4; ++i) {
      a[i] = *(const short8*)(As + (wm + i * 16 + l16) * 32 + quad * 8);
      b[i] = *(const short8*)(Bs + (wn + i * 16 + l16) * 32 + quad * 8);
    }
#pragma unroll
    for (int i = 0; i < 4; ++i)
#pragma unroll
      for (int j = 0; j < 4; ++j)
        acc[i][j] = __builtin_amdgcn_mfma_f32_16x16x32_bf16(a[i], b[j], acc[i][j], 0, 0, 0);
  }

#pragma unroll
  for (int j = 0; j < 4; ++j) {
    int gcol = n0 + wn + j * 16 + l16;
    int cn = gcol & 1023;
    float bb = bias[cn];
    int h = cn >> 6, d = cn & 63;
#pragma unroll
    for (int i = 0; i < 4; ++i) {
      int rbase = m0 + wm + i * 16 + quad * 4;
#pragma unroll
      for (int r = 0; r < 4; ++r) {
        int row = rbase + r;
        unsigned short hv = f2bf((acc[i][j][r] + bb) * scale);
        int bi = row >> 11, ni = row & 2047;
        size_t bh = (size_t)bi * 16 + h;
        if (mid == 2) {   // V^T B-frag, key order interleaved: pos=(jk&15)*2|(jk>>4)
          int nt = d >> 4, vl = d & 15;
          int kq = ni >> 5, jk = ni & 31;
          int pos = ((jk & 15) << 1) | (jk >> 4);
          Vo[((bh * 64 + kq) * 4 + nt) * 512 + (pos >> 3) * 128 + vl * 8 + (pos & 7)] = hv;
        } else {          // Q/K frag: block (bh*128 + tok16)*2 + kk
          int kfg = ni >> 4, tl = ni & 15;
          int kk = d >> 5, dq = (d & 31) >> 3, dj = d & 7;
          unsigned short* outp = mid == 0 ? Qo : Ko;
          outp[((bh * 128 + kfg) * 2 + kk) * 512 + dq * 128 + tl * 8 + dj] = hv;
        }
      }
    }
  }
}

// --------------------------------------------------------------- attention
// Block: 4 waves = 2 q-groups (32 rows) x 2 key-halves (32 kt each).
// Grid 2048 = 64 bh x 32 q-blocks of 64 rows. No barriers in main loop.
// P LDS round-trip pipelined across kt with parity double-buffer.
__global__ __launch_bounds__(256, 4) void attn_kernel(
    const unsigned short* __restrict__ Qs, const unsigned short* __restrict__ Ksw,
    const unsigned short* __restrict__ Vsw, unsigned short* __restrict__ O) {
  __shared__ __align__(16) char smem[20480];
  // phase 1: P double-buffer: wave w parity p at w*5120 + p*2560 bytes
  // phase 2 (epilogue): buf 2 x 32 x 68 f32 + lbuf 64 f32 (17664 B)

  const int tid = threadIdx.x, wave = tid >> 6, lane = tid & 63;
  const int quad = lane >> 4, l16 = lane & 15;
  const int wk = wave & 1, wqi = wave >> 1;
  int blk = blockIdx.x;
  int xcd = blk & 7, slot = blk >> 3;
  int bh = (slot & 7) * 8 + xcd, qb = slot >> 3;   // qb: 0..31 (64-row blocks)

  unsigned short* Pw0 = (unsigned short*)(smem + wave * 5120);
  unsigned short* Pw1 = (unsigned short*)(smem + wave * 5120 + 2560);

  // Q A-frags (2 row-tiles x 2 k-halves)
  short8 aq[2][2];
#pragma unroll
  for (int rt = 0; rt < 2; ++rt)
#pragma unroll
    for (int kk = 0; kk < 2; ++kk)
      aq[rt][kk] = *(const short8*)(Qs +
          (((size_t)bh * 128 + qb * 4 + wqi * 2 + rt) * 2 + kk) * 512 + lane * 8);

  short8 ones;
#pragma unroll
  for (int i = 0; i < 8; ++i) ones[i] = (short)0x3F80;   // bf16 1.0

  const float MSUB = 17.3123404906675611f;   // 12*log2(e); scores in log2 units
  floatx4 mneg;
#pragma unroll
  for (int i = 0; i < 4; ++i) mneg[i] = -MSUB;

  floatx4 acc_o[2][4] = {};
  floatx4 acc_l[2] = {};

  const unsigned short* kptr = Ksw + (size_t)bh * 128 * 2 * 512 + (size_t)wk * 32 * 2048;
  const unsigned short* vptr = Vsw + (size_t)bh * 64 * 4 * 512 + (size_t)wk * 32 * 2048;

  short8 kf[2][2], vf[4];
  floatx4 sacc[2][2];

  // ---- prologue: kti = 0
#pragma unroll
  for (int ct = 0; ct < 2; ++ct)
#pragma unroll
    for (int kk = 0; kk < 2; ++kk)
      kf[ct][kk] = *(const short8*)(kptr + (ct * 2 + kk) * 512 + lane * 8);
#pragma unroll
  for (int nt = 0; nt < 4; ++nt)
    vf[nt] = *(const short8*)(vptr + nt * 512 + lane * 8);
  kptr += 2048; vptr += 2048;
#pragma unroll
  for (int rt = 0; rt < 2; ++rt)
#pragma unroll
    for (int ct = 0; ct < 2; ++ct) {
      sacc[rt][ct] = __builtin_amdgcn_mfma_f32_16x16x32_bf16(aq[rt][0], kf[ct][0], mneg, 0, 0, 0);
      sacc[rt][ct] = __builtin_amdgcn_mfma_f32_16x16x32_bf16(aq[rt][1], kf[ct][1], sacc[rt][ct], 0, 0, 0);
    }
#pragma unroll
  for (int rt = 0; rt < 2; ++rt)
#pragma unroll
    for (int r = 0; r < 4; ++r) {
      float pe = EXP2F(sacc[rt][0][r]);
      float po = EXP2F(sacc[rt][1][r]);
      unsigned pk = __builtin_amdgcn_perm(__float_as_uint(po), __float_as_uint(pe), 0x07060302u);
      ((unsigned*)(Pw0 + (rt * 16 + quad * 4 + r) * 40))[l16] = pk;
    }

  // ---- main loop: kti = 1..31; PV(i-1) interleaved under QK(i)
  for (int kti = 1; kti < 32; ++kti) {
    unsigned short* Pprev = (kti & 1) ? Pw0 : Pw1;
    unsigned short* Pcur  = (kti & 1) ? Pw1 : Pw0;
    // K frag loads for this iter
    short8 kn[2][2];
#pragma unroll
    for (int ct = 0; ct < 2; ++ct)
#pragma unroll
      for (int kk = 0; kk < 2; ++kk)
        kn[ct][kk] = *(const short8*)(kptr + (ct * 2 + kk) * 512 + lane * 8);
    // issue P(i-1) reads early; consumed after QK
    short8 ap[2];
#pragma unroll
    for (int rt = 0; rt < 2; ++rt)
      ap[rt] = *(const short8*)(Pprev + (rt * 16 + l16) * 40 + quad * 8);
    // QK(i)
#pragma unroll
    for (int rt = 0; rt < 2; ++rt)
#pragma unroll
      for (int ct = 0; ct < 2; ++ct) {
        sacc[rt][ct] = __builtin_amdgcn_mfma_f32_16x16x32_bf16(aq[rt][0], kn[ct][0], mneg, 0, 0, 0);
        sacc[rt][ct] = __builtin_amdgcn_mfma_f32_16x16x32_bf16(aq[rt][1], kn[ct][1], sacc[rt][ct], 0, 0, 0);
      }
    // PV(i-1) with previous vf
#pragma unroll
    for (int rt = 0; rt < 2; ++rt) {
      acc_l[rt] = __builtin_amdgcn_mfma_f32_16x16x32_bf16(ap[rt], ones, acc_l[rt], 0, 0, 0);
#pragma unroll
      for (int nt = 0; nt < 4; ++nt)
        acc_o[rt][nt] = __builtin_amdgcn_mfma_f32_16x16x32_bf16(ap[rt], vf[nt], acc_o[rt][nt], 0, 0, 0);
    }
    // V frag loads for this iter (reuse vf regs after PV issue)
#pragma unroll
    for (int nt = 0; nt < 4; ++nt)
      vf[nt] = *(const short8*)(vptr + nt * 512 + lane * 8);
    kptr += 2048; vptr += 2048;
    // exp + pack + write P(i)
#pragma unroll
    for (int rt = 0; rt < 2; ++rt)
#pragma unroll
      for (int r = 0; r < 4; ++r) {
        float pe = EXP2F(sacc[rt][0][r]);
        float po = EXP2F(sacc[rt][1][r]);
        unsigned pk = __builtin_amdgcn_perm(__float_as_uint(po), __float_as_uint(pe), 0x07060302u);
        ((unsigned*)(Pcur + (rt * 16 + quad * 4 + r) * 40))[l16] = pk;
      }
  }
  // ---- epilogue PV for kti=31 (parity 1)
#pragma unroll
  for (int rt = 0; rt < 2; ++rt) {
    short8 apf = *(const short8*)(Pw1 + (rt * 16 + l16) * 40 + quad * 8);
    acc_l[rt] = __builtin_amdgcn_mfma_f32_16x16x32_bf16(apf, ones, acc_l[rt], 0, 0, 0);
#pragma unroll
    for (int nt = 0; nt < 4; ++nt)
      acc_o[rt][nt] = __builtin_amdgcn_mfma_f32_16x16x32_bf16(apf, vf[nt], acc_o[rt][nt], 0, 0, 0);
  }

  // ---- combine key halves, normalize, store
  float* buf = (float*)smem + wqi * 2176;          // 32 x 68 f32
  float* lbuf = (float*)(smem + 17408);            // 64 f32
  __syncthreads();
  if (wk == 1) {
#pragma unroll
    for (int rt = 0; rt < 2; ++rt)
#pragma unroll
      for (int r = 0; r < 4; ++r) {
        int row = rt * 16 + quad * 4 + r;
#pragma unroll
        for (int nt = 0; nt < 4; ++nt)
          buf[row * 68 + nt * 16 + l16] = acc_o[rt][nt][r];
        if (l16 == 0) lbuf[wqi * 32 + row] = acc_l[rt][r];
      }
  }
  __syncthreads();
  if (wk == 0) {
    const int b = bh >> 4, h = bh & 15;
#pragma unroll
    for (int rt = 0; rt < 2; ++rt)
#pragma unroll
      for (int r = 0; r < 4; ++r) {
        int row = rt * 16 + quad * 4 + r;
        float linv = 1.0f / (acc_l[rt][r] + lbuf[wqi * 32 + row]);
        int grow = qb * 64 + wqi * 32 + row;
#pragma unroll
        for (int nt = 0; nt < 4; ++nt) {
          float v = (acc_o[rt][nt][r] + buf[row * 68 + nt * 16 + l16]) * linv;
          O[((size_t)b * 2048 + grow) * 1024 + h * 64 + nt * 16 + l16] = f2bf(v);
        }
      }
  }
}

// ------------------------------------------------------------- output GEMM
__global__ __launch_bounds__(256) void gemm_out(
    const unsigned short* __restrict__ A, const unsigned short* __restrict__ BT,
    const float* __restrict__ bias, float* __restrict__ of) {
  constexpr int Kd = 1024;
  __shared__ unsigned short As[128 * 32];
  __shared__ unsigned short Bs[128 * 32];
  const int tid = threadIdx.x;
  const int wave = tid >> 6, lane = tid & 63;
  const int quad = lane >> 4, l16 = lane & 15;
  const int wm = (wave & 1) * 64, wn = (wave >> 1) * 64;
  const int m0 = blockIdx.x * 128, n0 = blockIdx.y * 128;

  floatx4 acc[4][4] = {};
  const unsigned short* Ag = A + (size_t)m0 * Kd;
  const unsigned short* Bg = BT + (size_t)n0 * Kd;

  for (int k0 = 0; k0 < Kd; k0 += 32) {
    __syncthreads();
#pragma unroll
    for (int p = 0; p < 2; ++p) {
      int c = wave * 128 + p * 64 + lane;
      int row = c >> 2, kp = (c & 3) * 8;
      async16(Ag + (size_t)row * Kd + k0 + kp, (char*)As + (size_t)(wave * 128 + p * 64) * 16);
      async16(Bg + (size_t)row * Kd + k0 + kp, (char*)Bs + (size_t)(wave * 128 + p * 64) * 16);
    }
    __syncthreads();
    short8 a[4], b[4];
#pragma unroll
    for (int i = 0; i < 4; ++i) {
      a[i] = *(const short8*)(As + (wm + i * 16 + l16) * 32 + quad * 8);
      b[i] = *(const short8*)(Bs + (wn + i * 16 + l16) * 32 + quad * 8);
    }
#pragma unroll
    for (int i = 0; i < 4; ++i)
#pragma unroll
      for (int j = 0; j < 4; ++j)
        acc[i][j] = __builtin_amdgcn_mfma_f32_16x16x32_bf16(a[i], b[j], acc[i][j], 0, 0, 0);
  }

#pragma unroll
  for (int j = 0; j < 4; ++j) {
    int col = n0 + wn + j * 16 + l16;
    float bb = bias[col];
#pragma unroll
    for (int i = 0; i < 4; ++i) {
      int rbase = m0 + wm + i * 16 + quad * 4;
#pragma unroll
      for (int r = 0; r < 4; ++r)
        of[(size_t)(rbase + r) * 1024 + col] = acc[i][j][r] + bb;
    }
  }
}

// ---------------------------------------------------------------- launch
extern "C" void kernel_launch(void* const* d_in, const int* in_sizes, int n_in,
                              void* d_out, int out_size, void* d_ws, size_t ws_size,
                              hipStream_t stream) {
  const float* x  = (const float*)d_in[0];
  const float* Wq = (const float*)d_in[1];
  const float* bq = (const float*)d_in[2];
  const float* Wk = (const float*)d_in[3];
  const float* bk = (const float*)d_in[4];
  const float* Wv = (const float*)d_in[5];
  const float* bv = (const float*)d_in[6];
  const float* Wo = (const float*)d_in[7];
  const float* bo = (const float*)d_in[8];

  char* ws = (char*)d_ws;
  unsigned short* xb  = (unsigned short*)(ws);                 // 16 MiB
  unsigned short* wqt = (unsigned short*)(ws + (16u << 20));   // 2 MiB each, contiguous
  unsigned short* wkt = (unsigned short*)(ws + (18u << 20));
  unsigned short* wvt = (unsigned short*)(ws + (20u << 20));
  unsigned short* wot = (unsigned short*)(ws + (22u << 20));
  unsigned short* Qb  = (unsigned short*)(ws + (24u << 20));   // 16 MiB each
  unsigned short* Kb  = (unsigned short*)(ws + (40u << 20));
  unsigned short* Vtb = (unsigned short*)(ws + (56u << 20));
  unsigned short* Ob  = (unsigned short*)(ws + (72u << 20));   // total 88 MiB

  prep_kernel<<<dim3(12288), 256, 0, stream>>>(x, xb, Wq, Wk, Wv, Wo, wqt, wkt, wvt, wot);
  gemm_qkv<<<dim3(64, 24), 256, 0, stream>>>(xb, wqt, bq, bk, bv, Qb, Kb, Vtb);
  attn_kernel<<<dim3(2048), 256, 0, stream>>>(Qb, Kb, Vtb, Ob);
  gemm_out<<<dim3(64, 8), 256, 0, stream>>>(Ob, wot, bo, (float*)d_out);
}

// Round 10
// 281.537 us; speedup vs baseline: 1.0767x; 1.0132x over previous
//
#include <hip/hip_runtime.h>
#include <hip/hip_bf16.h>
#include <cstdint>

// MultiHeadSelfAttention: B=4, N=2048, C=1024, H=16, D=64
// R10 (delta from R9):
//  - GEMMs: BK=64 (32KB LDS, [half][row][32] staging) -> 32 MFMA per barrier
//    pair instead of 16; halves barrier-drain count (K=1024 is barrier-bound).
//  - attn: K-frag register prefetch by 1 iteration (parity-unrolled x2,
//    compile-time indices); __launch_bounds__(256,3) for the extra regs.

typedef __attribute__((ext_vector_type(8))) short short8;    // 8 bf16
typedef __attribute__((ext_vector_type(4))) float floatx4;

#if __has_builtin(__builtin_amdgcn_exp2f)
#define EXP2F(x) __builtin_amdgcn_exp2f(x)
#else
#define EXP2F(x) __expf((x) * 0.6931471805599453f)
#endif

__device__ __forceinline__ unsigned short f2bf(float f) {
  unsigned u = __float_as_uint(f);
  unsigned r = u + 0x7fffu + ((u >> 16) & 1u);   // RNE
  return (unsigned short)(r >> 16);
}

__device__ __forceinline__ void async16(const void* g, void* l) {
  __builtin_amdgcn_global_load_lds(
      (__attribute__((address_space(1))) void*)(void*)(uintptr_t)g,
      (__attribute__((address_space(3))) void*)l, 16, 0, 0);
}

// ------------------------------------------- prep: x cvt + 4x W^T (merged)
__global__ __launch_bounds__(256) void prep_kernel(
    const float* __restrict__ x, unsigned short* __restrict__ xb,
    const float* __restrict__ W0, const float* __restrict__ W1,
    const float* __restrict__ W2, const float* __restrict__ W3,
    unsigned short* __restrict__ T0, unsigned short* __restrict__ T1,
    unsigned short* __restrict__ T2, unsigned short* __restrict__ T3) {
  const int tid = threadIdx.x;
  int blk = blockIdx.x;
  if (blk < 8192) {               // ---- x f32 -> bf16
    int i = (blk * 256 + tid) * 4;
    float4 v = *(const float4*)(x + i);
    ushort4 o;
    o.x = f2bf(v.x); o.y = f2bf(v.y); o.z = f2bf(v.z); o.w = f2bf(v.w);
    *(ushort4*)(xb + i) = o;
  } else {                        // ---- W transpose+convert, 32x32 tiles
    int t = blk - 8192;
    int z = t >> 10, tile = t & 1023;
    const float* W = z == 0 ? W0 : z == 1 ? W1 : z == 2 ? W2 : W3;
    unsigned short* T = z == 0 ? T0 : z == 1 ? T1 : z == 2 ? T2 : T3;
    __shared__ float tb[32][33];
    int tx = tid & 31, ty = tid >> 5;            // 32 x 8
    int bx = (tile & 31) * 32, by = (tile >> 5) * 32;
#pragma unroll
    for (int i = 0; i < 4; ++i)
      tb[ty + i * 8][tx] = W[(size_t)(by + ty + i * 8) * 1024 + bx + tx];
    __syncthreads();
#pragma unroll
    for (int i = 0; i < 4; ++i)
      T[(size_t)(bx + ty + i * 8) * 1024 + by + tx] = f2bf(tb[tx][ty + i * 8]);
  }
}

// ------------------------------------------- fused QKV projection (M x 3072)
// BK=64: As/Bs = [half][row][32] (16KB each). Direct-scatter epilogue.
__global__ __launch_bounds__(256) void gemm_qkv(
    const unsigned short* __restrict__ A, const unsigned short* __restrict__ BT,
    const float* __restrict__ bq, const float* __restrict__ bk,
    const float* __restrict__ bv,
    unsigned short* __restrict__ Qo, unsigned short* __restrict__ Ko,
    unsigned short* __restrict__ Vo) {
  constexpr int Kd = 1024;
  __shared__ unsigned short As[2 * 128 * 32];
  __shared__ unsigned short Bs[2 * 128 * 32];
  const int tid = threadIdx.x;
  const int wave = tid >> 6, lane = tid & 63;
  const int quad = lane >> 4, l16 = lane & 15;
  const int wm = (wave & 1) * 64, wn = (wave >> 1) * 64;
  const int m0 = blockIdx.x * 128, n0 = blockIdx.y * 128;
  const int mid = blockIdx.y >> 3;                 // 0=Q 1=K 2=V
  const float* bias = mid == 0 ? bq : mid == 1 ? bk : bv;
  const float scale = mid == 0 ? 0.180336880021082f : 1.0f;  // Q: 0.125*log2(e)

  floatx4 acc[4][4] = {};
  const unsigned short* Ag = A + (size_t)m0 * Kd;
  const unsigned short* Bg = BT + (size_t)n0 * Kd;

  for (int k0 = 0; k0 < Kd; k0 += 64) {
    __syncthreads();
#pragma unroll
    for (int p = 0; p < 4; ++p) {
      int c = (wave * 4 + p) * 64 + lane;
      int h = c >> 9, row = (c >> 2) & 127, kp = c & 3;
      async16(Ag + (size_t)row * Kd + k0 + h * 32 + kp * 8, (char*)As + (size_t)(wave * 4 + p) * 1024);
      async16(Bg + (size_t)row * Kd + k0 + h * 32 + kp * 8, (char*)Bs + (size_t)(wave * 4 + p) * 1024);
    }
    __syncthreads();
#pragma unroll
    for (int ks = 0; ks < 2; ++ks) {
      short8 a[4], b[4];
#pragma unroll
      for (int i = 0; i < 4; ++i) {
        a[i] = *(const short8*)(As + ks * 4096 + (wm + i * 16 + l16) * 32 + quad * 8);
        b[i] = *(const short8*)(Bs + ks * 4096 + (wn + i * 16 + l16) * 32 + quad * 8);
      }
#pragma unroll
      for (int i = 0; i < 4; ++i)
#pragma unroll
        for (int j = 0; j < 4; ++j)
          acc[i][j] = __builtin_amdgcn_mfma_f32_16x16x32_bf16(a[i], b[j], acc[i][j], 0, 0, 0);
    }
  }

#pragma unroll
  for (int j = 0; j < 4; ++j) {
    int gcol = n0 + wn + j * 16 + l16;
    int cn = gcol & 1023;
    float bb = bias[cn];
    int h = cn >> 6, d = cn & 63;
#pragma unroll
    for (int i = 0; i < 4; ++i) {
      int rbase = m0 + wm + i * 16 + quad * 4;
#pragma unroll
      for (int r = 0; r < 4; ++r) {
        int row = rbase + r;
        unsigned short hv = f2bf((acc[i][j][r] + bb) * scale);
        int bi = row >> 11, ni = row & 2047;
        size_t bh = (size_t)bi * 16 + h;
        if (mid == 2) {   // V^T B-frag, key order interleaved: pos=(jk&15)*2|(jk>>4)
          int nt = d >> 4, vl = d & 15;
          int kq = ni >> 5, jk = ni & 31;
          int pos = ((jk & 15) << 1) | (jk >> 4);
          Vo[((bh * 64 + kq) * 4 + nt) * 512 + (pos >> 3) * 128 + vl * 8 + (pos & 7)] = hv;
        } else {          // Q/K frag: block (bh*128 + tok16)*2 + kk
          int kfg = ni >> 4, tl = ni & 15;
          int kk = d >> 5, dq = (d & 31) >> 3, dj = d & 7;
          unsigned short* outp = mid == 0 ? Qo : Ko;
          outp[((bh * 128 + kfg) * 2 + kk) * 512 + dq * 128 + tl * 8 + dj] = hv;
        }
      }
    }
  }
}

// --------------------------------------------------------------- attention
// Block: 4 waves = 2 q-groups (32 rows) x 2 key-halves (32 kt each).
// Grid 2048. No barriers in main loop. P parity double-buffer (as R9) +
// K-frag register prefetch by 1 kt (parity-unrolled, compile-time indices).
__global__ __launch_bounds__(256, 3) void attn_kernel(
    const unsigned short* __restrict__ Qs, const unsigned short* __restrict__ Ksw,
    const unsigned short* __restrict__ Vsw, unsigned short* __restrict__ O) {
  __shared__ __align__(16) char smem[20480];

  const int tid = threadIdx.x, wave = tid >> 6, lane = tid & 63;
  const int quad = lane >> 4, l16 = lane & 15;
  const int wk = wave & 1, wqi = wave >> 1;
  int blk = blockIdx.x;
  int xcd = blk & 7, slot = blk >> 3;
  int bh = (slot & 7) * 8 + xcd, qb = slot >> 3;   // qb: 0..31 (64-row blocks)

  unsigned short* Pw0 = (unsigned short*)(smem + wave * 5120);
  unsigned short* Pw1 = (unsigned short*)(smem + wave * 5120 + 2560);

  // Q A-frags (2 row-tiles x 2 k-halves)
  short8 aq[2][2];
#pragma unroll
  for (int rt = 0; rt < 2; ++rt)
#pragma unroll
    for (int kk = 0; kk < 2; ++kk)
      aq[rt][kk] = *(const short8*)(Qs +
          (((size_t)bh * 128 + qb * 4 + wqi * 2 + rt) * 2 + kk) * 512 + lane * 8);

  short8 ones;
#pragma unroll
  for (int i = 0; i < 8; ++i) ones[i] = (short)0x3F80;   // bf16 1.0

  const float MSUB = 17.3123404906675611f;   // 12*log2(e); scores in log2 units
  floatx4 mneg;
#pragma unroll
  for (int i = 0; i < 4; ++i) mneg[i] = -MSUB;

  floatx4 acc_o[2][4] = {};
  floatx4 acc_l[2] = {};

  const unsigned short* kptr0 = Ksw + (size_t)bh * 128 * 2 * 512 + (size_t)wk * 32 * 2048;
  const unsigned short* vptr0 = Vsw + (size_t)bh * 64 * 4 * 512 + (size_t)wk * 32 * 2048;

  short8 kf0[2][2], kf1[2][2], vf[4];
  floatx4 sacc[2][2];

#define LOAD_KF(dst, KT)                                                          \
  {                                                                               \
    _Pragma("unroll") for (int ct = 0; ct < 2; ++ct)                              \
        _Pragma("unroll") for (int kk = 0; kk < 2; ++kk)                          \
            dst[ct][kk] = *(const short8*)(kptr0 + (size_t)(KT)*2048 +            \
                                           (ct * 2 + kk) * 512 + lane * 8);       \
  }
#define LOAD_VF(KT)                                                               \
  {                                                                               \
    _Pragma("unroll") for (int nt = 0; nt < 4; ++nt)                              \
        vf[nt] = *(const short8*)(vptr0 + (size_t)(KT)*2048 + nt * 512 + lane * 8); \
  }
#define QK_BLOCK(KF)                                                              \
  {                                                                               \
    _Pragma("unroll") for (int rt = 0; rt < 2; ++rt)                              \
        _Pragma("unroll") for (int ct = 0; ct < 2; ++ct) {                        \
      sacc[rt][ct] = __builtin_amdgcn_mfma_f32_16x16x32_bf16(aq[rt][0], KF[ct][0], mneg, 0, 0, 0); \
      sacc[rt][ct] = __builtin_amdgcn_mfma_f32_16x16x32_bf16(aq[rt][1], KF[ct][1], sacc[rt][ct], 0, 0, 0); \
    }                                                                             \
  }
#define EXP_WRITE(PBUF)                                                           \
  {                                                                               \
    _Pragma("unroll") for (int rt = 0; rt < 2; ++rt)                              \
        _Pragma("unroll") for (int r = 0; r < 4; ++r) {                           \
      float pe = EXP2F(sacc[rt][0][r]);                                           \
      float po = EXP2F(sacc[rt][1][r]);                                           \
      unsigned pk = __builtin_amdgcn_perm(__float_as_uint(po), __float_as_uint(pe), 0x07060302u); \
      ((unsigned*)((PBUF) + (rt * 16 + quad * 4 + r) * 40))[l16] = pk;            \
    }                                                                             \
  }
#define PV_BLOCK(PBUF)                                                            \
  {                                                                               \
    _Pragma("unroll") for (int rt = 0; rt < 2; ++rt) {                            \
      short8 ap = *(const short8*)((PBUF) + (rt * 16 + l16) * 40 + quad * 8);     \
      acc_l[rt] = __builtin_amdgcn_mfma_f32_16x16x32_bf16(ap, ones, acc_l[rt], 0, 0, 0); \
      _Pragma("unroll") for (int nt = 0; nt < 4; ++nt)                            \
          acc_o[rt][nt] = __builtin_amdgcn_mfma_f32_16x16x32_bf16(ap, vf[nt], acc_o[rt][nt], 0, 0, 0); \
    }                                                                             \
  }

  // ---- prologue: kt=0 (kf0), prefetch kt=1 (kf1), vf=V(0)
  LOAD_KF(kf0, 0);
  LOAD_KF(kf1, 1);
  LOAD_VF(0);
  QK_BLOCK(kf0);
  EXP_WRITE(Pw0);

  // ---- main: i = 2it+1 (odd: cur=kf1, next->kf0, Pprev=Pw0, Pcur=Pw1)
  //            i = 2it+2 (even: cur=kf0, next->kf1, Pprev=Pw1, Pcur=Pw0)
  for (int it = 0; it < 15; ++it) {
    const int i1 = 2 * it + 1, i2 = 2 * it + 2;
    // odd sub-iter
    LOAD_KF(kf0, i1 + 1);
    QK_BLOCK(kf1);
    PV_BLOCK(Pw0);          // PV(i1-1) with vf = V(i1-1)
    LOAD_VF(i1);
    EXP_WRITE(Pw1);
    // even sub-iter
    LOAD_KF(kf1, i2 + 1);
    QK_BLOCK(kf0);
    PV_BLOCK(Pw1);          // PV(i2-1)
    LOAD_VF(i2);
    EXP_WRITE(Pw0);
  }
  // ---- tail: i = 31 (odd roles, no prefetch)
  QK_BLOCK(kf1);
  PV_BLOCK(Pw0);            // PV(30)
  LOAD_VF(31);
  EXP_WRITE(Pw1);
  PV_BLOCK(Pw1);            // PV(31)

#undef LOAD_KF
#undef LOAD_VF
#undef QK_BLOCK
#undef EXP_WRITE
#undef PV_BLOCK

  // ---- combine key halves, normalize, store
  float* buf = (float*)smem + wqi * 2176;          // 32 x 68 f32
  float* lbuf = (float*)(smem + 17408);            // 64 f32
  __syncthreads();
  if (wk == 1) {
#pragma unroll
    for (int rt = 0; rt < 2; ++rt)
#pragma unroll
      for (int r = 0; r < 4; ++r) {
        int row = rt * 16 + quad * 4 + r;
#pragma unroll
        for (int nt = 0; nt < 4; ++nt)
          buf[row * 68 + nt * 16 + l16] = acc_o[rt][nt][r];
        if (l16 == 0) lbuf[wqi * 32 + row] = acc_l[rt][r];
      }
  }
  __syncthreads();
  if (wk == 0) {
    const int b = bh >> 4, h = bh & 15;
#pragma unroll
    for (int rt = 0; rt < 2; ++rt)
#pragma unroll
      for (int r = 0; r < 4; ++r) {
        int row = rt * 16 + quad * 4 + r;
        float linv = 1.0f / (acc_l[rt][r] + lbuf[wqi * 32 + row]);
        int grow = qb * 64 + wqi * 32 + row;
#pragma unroll
        for (int nt = 0; nt < 4; ++nt) {
          float v = (acc_o[rt][nt][r] + buf[row * 68 + nt * 16 + l16]) * linv;
          O[((size_t)b * 2048 + grow) * 1024 + h * 64 + nt * 16 + l16] = f2bf(v);
        }
      }
  }
}

// ------------------------------------------------------------- output GEMM
// BK=64, same staging as gemm_qkv.
__global__ __launch_bounds__(256) void gemm_out(
    const unsigned short* __restrict__ A, const unsigned short* __restrict__ BT,
    const float* __restrict__ bias, float* __restrict__ of) {
  constexpr int Kd = 1024;
  __shared__ unsigned short As[2 * 128 * 32];
  __shared__ unsigned short Bs[2 * 128 * 32];
  const int tid = threadIdx.x;
  const int wave = tid >> 6, lane = tid & 63;
  const int quad = lane >> 4, l16 = lane & 15;
  const int wm = (wave & 1) * 64, wn = (wave >> 1) * 64;
  const int m0 = blockIdx.x * 128, n0 = blockIdx.y * 128;

  floatx4 acc[4][4] = {};
  const unsigned short* Ag = A + (size_t)m0 * Kd;
  const unsigned short* Bg = BT + (size_t)n0 * Kd;

  for (int k0 = 0; k0 < Kd; k0 += 64) {
    __syncthreads();
#pragma unroll
    for (int p = 0; p < 4; ++p) {
      int c = (wave * 4 + p) * 64 + lane;
      int h = c >> 9, row = (c >> 2) & 127, kp = c & 3;
      async16(Ag + (size_t)row * Kd + k0 + h * 32 + kp * 8, (char*)As + (size_t)(wave * 4 + p) * 1024);
      async16(Bg + (size_t)row * Kd + k0 + h * 32 + kp * 8, (char*)Bs + (size_t)(wave * 4 + p) * 1024);
    }
    __syncthreads();
#pragma unroll
    for (int ks = 0; ks < 2; ++ks) {
      short8 a[4], b[4];
#pragma unroll
      for (int i = 0; i < 4; ++i) {
        a[i] = *(const short8*)(As + ks * 4096 + (wm + i * 16 + l16) * 32 + quad * 8);
        b[i] = *(const short8*)(Bs + ks * 4096 + (wn + i * 16 + l16) * 32 + quad * 8);
      }
#pragma unroll
      for (int i = 0; i < 4; ++i)
#pragma unroll
        for (int j = 0; j < 4; ++j)
          acc[i][j] = __builtin_amdgcn_mfma_f32_16x16x32_bf16(a[i], b[j], acc[i][j], 0, 0, 0);
    }
  }

#pragma unroll
  for (int j = 0; j < 4; ++j) {
    int col = n0 + wn + j * 16 + l16;
    float bb = bias[col];
#pragma unroll
    for (int i = 0; i < 4; ++i) {
      int rbase = m0 + wm + i * 16 + quad * 4;
#pragma unroll
      for (int r = 0; r < 4; ++r)
        of[(size_t)(rbase + r) * 1024 + col] = acc[i][j][r] + bb;
    }
  }
}

// ---------------------------------------------------------------- launch
extern "C" void kernel_launch(void* const* d_in, const int* in_sizes, int n_in,
                              void* d_out, int out_size, void* d_ws, size_t ws_size,
                              hipStream_t stream) {
  const float* x  = (const float*)d_in[0];
  const float* Wq = (const float*)d_in[1];
  const float* bq = (const float*)d_in[2];
  const float* Wk = (const float*)d_in[3];
  const float* bk = (const float*)d_in[4];
  const float* Wv = (const float*)d_in[5];
  const float* bv = (const float*)d_in[6];
  const float* Wo = (const float*)d_in[7];
  const float* bo = (const float*)d_in[8];

  char* ws = (char*)d_ws;
  unsigned short* xb  = (unsigned short*)(ws);                 // 16 MiB
  unsigned short* wqt = (unsigned short*)(ws + (16u << 20));   // 2 MiB each, contiguous
  unsigned short* wkt = (unsigned short*)(ws + (18u << 20));
  unsigned short* wvt = (unsigned short*)(ws + (20u << 20));
  unsigned short* wot = (unsigned short*)(ws + (22u << 20));
  unsigned short* Qb  = (unsigned short*)(ws + (24u << 20));   // 16 MiB each
  unsigned short* Kb  = (unsigned short*)(ws + (40u << 20));
  unsigned short* Vtb = (unsigned short*)(ws + (56u << 20));
  unsigned short* Ob  = (unsigned short*)(ws + (72u << 20));   // total 88 MiB

  prep_kernel<<<dim3(12288), 256, 0, stream>>>(x, xb, Wq, Wk, Wv, Wo, wqt, wkt, wvt, wot);
  gemm_qkv<<<dim3(64, 24), 256, 0, stream>>>(xb, wqt, bq, bk, bv, Qb, Kb, Vtb);
  attn_kernel<<<dim3(2048), 256, 0, stream>>>(Qb, Kb, Vtb, Ob);
  gemm_out<<<dim3(64, 8), 256, 0, stream>>>(Ob, wot, bo, (float*)d_out);
}